// Round 8
// baseline (434.466 us; speedup 1.0000x reference)
//
#include <hip/hip_runtime.h>

// Problem constants
#define G 4
#define M 4096
#define D 128
#define NQ 16384
#define NROWS 65536                      // total query rows (NQ * G)
#define OFF_IND 8388608                  // NROWS * D
#define OFF_CNT (OFF_IND + NROWS)
#define DELTA 0.08f                      // fp16 single-product margin (12 sigma)

typedef unsigned int u32;
typedef unsigned short u16;
typedef __attribute__((ext_vector_type(8))) _Float16 f16x8;
typedef __attribute__((ext_vector_type(4))) float f32x4;
typedef __attribute__((ext_vector_type(16))) float f32x16;

union hpack { f16x8 v; u32 u[4]; _Float16 h[8]; };

// async global->LDS, 16B per lane; lds dst = wave-uniform base (+ lane*16 by HW)
__device__ __forceinline__ void gload16(const void* gsrc, void* ldsdst) {
    __builtin_amdgcn_global_load_lds(
        (const __attribute__((address_space(1))) u32*)gsrc,
        (__attribute__((address_space(3))) u32*)ldsdst,
        16, 0, 0);
}

// ---------------- fast path ----------------

// prep_all: emb -> efrag (fp16 fragments) + e2f (fp32 row norms) + counts copy
// + flagcnt=0.  efrag chunk (g, mt) of 32 m's at (g*128+mt)*2048 u32 (8 KB).
// Within chunk: [kk*64 + lane] f16x8; lane: m=mt*32+(lane&31), k=kk*16+(lane>>5)*8.
__global__ __launch_bounds__(256) void prep_all(const float* __restrict__ emb,
                                                const float* __restrict__ cnt,
                                                u32* __restrict__ efrag,
                                                float* __restrict__ e2f,
                                                float* __restrict__ outcnt,
                                                int* __restrict__ flagcnt) {
    __shared__ float part[4][32];
    const int tid = threadIdx.x, w = tid >> 6;
    const int g = blockIdx.x >> 7, mt = blockIdx.x & 127;
    u32* chunk = efrag + (size_t)(g * 128 + mt) * 2048;
    float ss = 0.f;
#pragma unroll
    for (int rep = 0; rep < 2; ++rep) {
        const int idx = rep * 256 + tid;           // (kk, lane) slot, 0..511
        const int kk = idx >> 6, lane = idx & 63;
        const int m = mt * 32 + (lane & 31);
        const int k = kk * 16 + (lane >> 5) * 8;
        const float* src = emb + ((size_t)g * M + m) * D + k;
        const float4 a = *(const float4*)src;
        const float4 b = *(const float4*)(src + 4);
        const float v[8] = {a.x, a.y, a.z, a.w, b.x, b.y, b.z, b.w};
        hpack p;
#pragma unroll
        for (int i = 0; i < 8; ++i) {
            ss = fmaf(v[i], v[i], ss);
            p.h[i] = (_Float16)v[i];               // RNE f32->f16
        }
        *(uint4*)(chunk + (size_t)(kk * 64 + lane) * 4) =
            make_uint4(p.u[0], p.u[1], p.u[2], p.u[3]);
    }
    // e2: each (rep,lane) pair covered 16 elems of row m; lanes l and l+32 share m
    ss += __shfl_xor(ss, 32, 64);
    if ((tid & 63) < 32) part[w][tid & 31] = ss;
    __syncthreads();
    if (tid < 32)
        e2f[(size_t)g * M + mt * 32 + tid] =
            part[0][tid] + part[1][tid] + part[2][tid] + part[3][tid];
    else if (tid >= 64 && tid < 96)                // counts copy (32 per block)
        outcnt[(size_t)g * M + mt * 32 + (tid - 64)] = cnt[(size_t)g * M + mt * 32 + (tid - 64)];
    if (blockIdx.x == 0 && tid == 0) *flagcnt = 0;
}

// fp16 32x32x16 MFMA distance+argmin. Block = (g, half, qb): 128 queries x 2048 m.
// Single product fp16(-2x) * fp16(e); margin DELTA guards exactness via recheck.
__global__ __launch_bounds__(256, 4) void vq_mfma5(const float* __restrict__ x,
                                                   const u32* __restrict__ efrag,
                                                   const float* __restrict__ e2f,
                                                   float* __restrict__ out) {
    __shared__ float e2s[2048];       // 8 KB
    __shared__ u32 ebuf[2][2048];     // 2 x 8 KB double buffer

    const int tid = threadIdx.x, w = tid >> 6, lane = tid & 63;
    const int combo = blockIdx.x & 7;              // XCD round-robin friendly
    const int g = combo >> 1, half = combo & 1;
    const int qb = blockIdx.x >> 3;                // 0..127
    const int rot = (qb * 23) & 63;                // chunk-ring stagger

    const float* e2g = e2f + (size_t)g * M + half * 2048;
    for (int i = tid; i < 512; i += 256) ((float4*)e2s)[i] = ((const float4*)e2g)[i];

    // A fragments (this wave's 32 queries): row=lane&31, k=kk*16+(lane>>5)*8
    const int qrow = qb * 128 + w * 32 + (lane & 31);
    f16x8 xh[8];
#pragma unroll
    for (int kk = 0; kk < 8; ++kk) {
        const int k = kk * 16 + (lane >> 5) * 8;
        const float* src = x + ((size_t)qrow * 4 + g) * D + k;
        const float4 a = *(const float4*)src;
        const float4 b = *(const float4*)(src + 4);
        const float v[8] = {a.x, a.y, a.z, a.w, b.x, b.y, b.z, b.w};
        hpack p;
#pragma unroll
        for (int i = 0; i < 8; ++i) p.h[i] = (_Float16)(-2.0f * v[i]);
        xh[kk] = p.v;
    }

    float b1[16], b2[16];
    int i1[16];
#pragma unroll
    for (int r = 0; r < 16; ++r) { b1[r] = 3.4e38f; b2[r] = 3.4e38f; i1[r] = 0; }

    const char* eg = (const char*)(efrag + (size_t)(g * 128 + half * 64) * 2048);
    // prologue: stage chunk rot (8 KB, 2 x 1KB per wave)
#pragma unroll
    for (int j = 0; j < 2; ++j)
        gload16(eg + (size_t)rot * 8192 + w * 2048 + j * 1024 + lane * 16,
                (char*)ebuf[0] + w * 2048 + j * 1024);
    __syncthreads();   // drains vmcnt(0)

    for (int t = 0; t < 64; ++t) {
        const int cur = t & 1;
        const int cidx = (t + rot) & 63;
        if (t < 63) {                 // issue next-chunk async loads early
            const char* src = eg + (size_t)(((t + 1 + rot) & 63)) * 8192;
#pragma unroll
            for (int j = 0; j < 2; ++j)
                gload16(src + w * 2048 + j * 1024 + lane * 16,
                        (char*)ebuf[cur ^ 1] + w * 2048 + j * 1024);
        }
        const f16x8* bp = (const f16x8*)ebuf[cur];
        const float e2c = e2s[cidx * 32 + (lane & 31)];
        f32x16 acc;
#pragma unroll
        for (int r = 0; r < 16; ++r) acc[r] = e2c;   // fold e2[m] into C-init
#pragma unroll
        for (int kk = 0; kk < 8; ++kk)
            acc = __builtin_amdgcn_mfma_f32_32x32x16_f16(xh[kk], bp[kk * 64 + lane],
                                                         acc, 0, 0, 0);
        const int mcol = half * 2048 + cidx * 32 + (lane & 31);
#pragma unroll
        for (int r = 0; r < 16; ++r) {
            const float s = acc[r];
            b2[r] = __builtin_amdgcn_fmed3f(s, b1[r], b2[r]);  // 2nd-best in 1 op
            i1[r] = (s < b1[r]) ? mcol : i1[r];
            b1[r] = fminf(b1[r], s);
        }
        __syncthreads();              // drains vmcnt(0): next chunk staged
    }

    // reduce over the 32 m-lanes within each half-wave; lowest-index tie-break.
    // Write per-query partial {v1, v2, idx} into the query's own x_quant row header.
#pragma unroll
    for (int r = 0; r < 16; ++r) {
        float v1 = b1[r], v2 = b2[r];
        int j1 = i1[r];
#pragma unroll
        for (int off = 1; off < 32; off <<= 1) {
            const float o1 = __shfl_xor(v1, off, 64);
            const int   oj = __shfl_xor(j1, off, 64);
            const float o2 = __shfl_xor(v2, off, 64);
            v2 = fminf(fminf(v2, o2), fmaxf(v1, o1));
            if (o1 < v1 || (o1 == v1 && oj < j1)) { v1 = o1; j1 = oj; }
        }
        if ((lane & 31) == 0) {
            const int q = qb * 128 + w * 32 + (r & 3) + 8 * (r >> 2) + 4 * (lane >> 5);
            float* rowbase = out + (size_t)(q * 4 + g) * D;
            *(float4*)(rowbase + half * 4) =
                make_float4(v1, v2, __int_as_float(j1), 0.f);
        }
    }
}

// gather_merge: per query merge the two half-partials (stored in its x_quant row),
// write ind + count (or flag), then gather the embedding row into x_quant.
__global__ __launch_bounds__(256) void gather_merge(const float* __restrict__ emb,
                                                    float* __restrict__ out,
                                                    int* __restrict__ flagcnt,
                                                    int* __restrict__ flaglist) {
    __shared__ int sm[64];
    const int tid = threadIdx.x;
    const int qid0 = blockIdx.x * 64;               // 64 queries per block, same g
    const int g = qid0 >> 14;
    if (tid < 64) {
        const int qid = qid0 + tid;
        const int n = qid & 16383;
        float* rowbase = out + (size_t)(n * 4 + g) * D;
        const float4 p0 = *(const float4*)(rowbase);
        const float4 p1 = *(const float4*)(rowbase + 4);
        const float v1a = p0.x, v2a = p0.y;
        const float v1b = p1.x, v2b = p1.y;
        const int ia = __float_as_int(p0.z), ib = __float_as_int(p1.z);
        const float v1 = fminf(v1a, v1b);
        const int i = (v1b < v1a) ? ib : ia;        // tie -> half0 (lower index)
        const float v2 = fminf(fminf(v2a, v2b), fmaxf(v1a, v1b));
        out[(size_t)OFF_IND + (size_t)n * 4 + g] = (float)i;   // approx for flagged
        if (v2 - v1 > DELTA) {
            atomicAdd(out + OFF_CNT + (size_t)g * M + i, 1.0f);
        } else {
            const int pos = atomicAdd(flagcnt, 1);
            flaglist[pos] = qid;                    // recheck fixes ind/count/row
        }
        sm[tid] = i;
    }
    __syncthreads();
#pragma unroll
    for (int p = 0; p < 8; ++p) {
        const int t2 = p * 8 + (tid >> 5);
        const int lane = tid & 31;
        const int n = (qid0 + t2) & 16383;
        const int m = sm[t2];
        const float4 v = ((const float4*)(emb + ((size_t)g * M + m) * D))[lane];
        ((float4*)(out + (size_t)(n * 4 + g) * D))[lane] = v;
    }
}

// exact fp64 rescan for flagged (near-tie) queries; also repairs x_quant row.
__global__ __launch_bounds__(256) void recheck2(const float* __restrict__ x,
                                                const float* __restrict__ emb,
                                                const int* __restrict__ flagcnt,
                                                const int* __restrict__ flaglist,
                                                float* __restrict__ out) {
    __shared__ float xs[D];
    __shared__ double wv[4];
    __shared__ int wi[4];
    __shared__ int sbj;
    const int tid = threadIdx.x;
    int nf = *flagcnt;
    if (nf > NROWS) nf = NROWS;
    for (int it = blockIdx.x; it < nf; it += gridDim.x) {
        const int qid = flaglist[it];
        const int g = qid >> 14, n = qid & 16383;
        __syncthreads();
        if (tid < 32) ((float4*)xs)[tid] = ((const float4*)(x + ((size_t)n * 4 + g) * D))[tid];
        __syncthreads();
        double best = 1e300;
        int bi = 0;
        for (int j = 0; j < 16; ++j) {
            const int m = tid + j * 256;
            const float* e = emb + ((size_t)g * M + m) * D;
            double dot = 0.0, ee = 0.0;
            for (int k = 0; k < D; k += 4) {
                const float4 ev = *(const float4*)(e + k);
                const double e0 = ev.x, e1 = ev.y, e2v = ev.z, e3 = ev.w;
                dot = fma((double)xs[k + 0], e0, dot);
                dot = fma((double)xs[k + 1], e1, dot);
                dot = fma((double)xs[k + 2], e2v, dot);
                dot = fma((double)xs[k + 3], e3, dot);
                ee = fma(e0, e0, ee); ee = fma(e1, e1, ee);
                ee = fma(e2v, e2v, ee); ee = fma(e3, e3, ee);
            }
            const double s = ee - 2.0 * dot;
            if (s < best) { best = s; bi = m; }
        }
        for (int off = 1; off < 64; off <<= 1) {
            const double ob = __shfl_xor(best, off, 64);
            const int oi = __shfl_xor(bi, off, 64);
            if (ob < best || (ob == best && oi < bi)) { best = ob; bi = oi; }
        }
        if ((tid & 63) == 0) { wv[tid >> 6] = best; wi[tid >> 6] = bi; }
        __syncthreads();
        if (tid == 0) {
            double bv = wv[0];
            int bj = wi[0];
            for (int u = 1; u < 4; ++u)
                if (wv[u] < bv || (wv[u] == bv && wi[u] < bj)) { bv = wv[u]; bj = wi[u]; }
            out[(size_t)OFF_IND + (size_t)n * 4 + g] = (float)bj;
            atomicAdd(out + OFF_CNT + (size_t)g * M + bj, 1.0f);
            sbj = bj;
        }
        __syncthreads();
        if (tid < 32) {
            const int bj = sbj;
            ((float4*)(out + (size_t)(n * 4 + g) * D))[tid] =
                ((const float4*)(emb + ((size_t)g * M + bj) * D))[tid];
        }
    }
}

// ---------------- fallback (exact fp64 path, used only if ws too small) ----------------

#define QT 64
#define MT 128
#define KT 32
#define XPAD 132
#define EPAD 36

__global__ __launch_bounds__(256) void e2d_kernel(const float* __restrict__ emb,
                                                  double* __restrict__ e2) {
    int row = blockIdx.x * 4 + (threadIdx.x >> 6);
    int lane = threadIdx.x & 63;
    const float2 v = ((const float2*)(emb + (size_t)row * D))[lane];
    double s = (double)v.x * (double)v.x + (double)v.y * (double)v.y;
#pragma unroll
    for (int off = 1; off < 64; off <<= 1) s += __shfl_xor(s, off, 64);
    if (lane == 0) e2[row] = s;
}

__global__ __launch_bounds__(256) void argmin_kernel(const float* __restrict__ x,
                                                     const float* __restrict__ emb,
                                                     const double* __restrict__ e2,
                                                     float* __restrict__ out) {
    __shared__ float xs[QT][XPAD];
    __shared__ float es[MT][EPAD];
    const int g = blockIdx.x >> 8;
    const int n0 = (blockIdx.x & 255) * QT;
    const int tid = threadIdx.x;
    const int tm = tid & 15;
    const int tq = tid >> 4;
#pragma unroll
    for (int it = 0; it < 8; ++it) {
        int idx = it * 256 + tid;
        int r = idx >> 5, c2 = idx & 31;
        const float4 v = ((const float4*)(x + ((size_t)((n0 + r) * 4 + g)) * D))[c2];
        *(float4*)&xs[r][c2 * 4] = v;
    }
    double best[4];
    int bm[4];
#pragma unroll
    for (int qi = 0; qi < 4; ++qi) { best[qi] = 1e300; bm[qi] = 0; }
    const double* e2g = e2 + (size_t)g * M;
    const float* eg = emb + (size_t)g * M * D;
    for (int mc = 0; mc < M / MT; ++mc) {
        const int m0 = mc * MT;
        double acc[4][8];
#pragma unroll
        for (int qi = 0; qi < 4; ++qi)
#pragma unroll
            for (int mi = 0; mi < 8; ++mi) acc[qi][mi] = 0.0;
        for (int kc = 0; kc < D / KT; ++kc) {
            __syncthreads();
#pragma unroll
            for (int it = 0; it < 4; ++it) {
                int idx = it * 256 + tid;
                int r = idx >> 3, c2 = idx & 7;
                const float4 v = ((const float4*)(eg + (size_t)(m0 + r) * D + kc * KT))[c2];
                *(float4*)&es[r][c2 * 4] = v;
            }
            __syncthreads();
#pragma unroll
            for (int kk = 0; kk < KT; kk += 4) {
                double xv[4][4];
#pragma unroll
                for (int qi = 0; qi < 4; ++qi) {
                    const float4 v = *(const float4*)&xs[tq + 16 * qi][kc * KT + kk];
                    xv[qi][0] = v.x; xv[qi][1] = v.y; xv[qi][2] = v.z; xv[qi][3] = v.w;
                }
#pragma unroll
                for (int mi = 0; mi < 8; ++mi) {
                    const float4 v = *(const float4*)&es[tm + 16 * mi][kk];
                    const double e0 = v.x, e1 = v.y, e2v = v.z, e3 = v.w;
#pragma unroll
                    for (int qi = 0; qi < 4; ++qi) {
                        acc[qi][mi] = fma(xv[qi][0], e0, acc[qi][mi]);
                        acc[qi][mi] = fma(xv[qi][1], e1, acc[qi][mi]);
                        acc[qi][mi] = fma(xv[qi][2], e2v, acc[qi][mi]);
                        acc[qi][mi] = fma(xv[qi][3], e3, acc[qi][mi]);
                    }
                }
            }
        }
#pragma unroll
        for (int mi = 0; mi < 8; ++mi) {
            const int m = m0 + tm + 16 * mi;
            const double e2m = e2g[m];
#pragma unroll
            for (int qi = 0; qi < 4; ++qi) {
                const double s = e2m - 2.0 * acc[qi][mi];
                if (s < best[qi]) { best[qi] = s; bm[qi] = m; }
            }
        }
    }
#pragma unroll
    for (int qi = 0; qi < 4; ++qi) {
        double v = best[qi];
        int i = bm[qi];
#pragma unroll
        for (int off = 1; off < 16; off <<= 1) {
            const double ov = __shfl_xor(v, off, 64);
            const int oi = __shfl_xor(i, off, 64);
            if (ov < v || (ov == v && oi < i)) { v = ov; i = oi; }
        }
        if (tm == 0) {
            const int n = n0 + tq + 16 * qi;
            out[(size_t)OFF_IND + (size_t)n * 4 + g] = (float)i;
            atomicAdd(out + OFF_CNT + (size_t)g * M + i, 1.0f);
        }
    }
}

__global__ __launch_bounds__(256) void gather_kernel(const float* __restrict__ emb,
                                                     const float* __restrict__ indf,
                                                     float* __restrict__ xq) {
    const int rid = blockIdx.x * 8 + (threadIdx.x >> 5);
    const int lane = threadIdx.x & 31;
    const int g = rid & 3;
    const int m = (int)indf[rid];
    const float4 v = ((const float4*)(emb + ((size_t)g * M + m) * D))[lane];
    ((float4*)(xq + (size_t)rid * D))[lane] = v;
}

// ---------------- launch ----------------

extern "C" void kernel_launch(void* const* d_in, const int* in_sizes, int n_in,
                              void* d_out, int out_size, void* d_ws, size_t ws_size,
                              hipStream_t stream) {
    const float* x   = (const float*)d_in[0];
    const float* emb = (const float*)d_in[1];
    const float* cnt = (const float*)d_in[2];
    float* out = (float*)d_out;

    if (ws_size >= 4522240) {
        u32*   efrag    = (u32*)d_ws;                          // [0, 4194304)  4 MB
        float* e2fp     = (float*)((char*)d_ws + 4194304);     // 64 KB
        int*   flagcnt  = (int*)((char*)d_ws + 4259840);       // 4 B (pad 256)
        int*   flaglist = (int*)((char*)d_ws + 4260096);       // 256 KB -> end 4522240

        hipLaunchKernelGGL(prep_all, dim3(512), dim3(256), 0, stream,
                           emb, cnt, efrag, e2fp, out + OFF_CNT, flagcnt);
        hipLaunchKernelGGL(vq_mfma5, dim3(1024), dim3(256), 0, stream,
                           x, efrag, e2fp, out);
        hipLaunchKernelGGL(gather_merge, dim3(1024), dim3(256), 0, stream,
                           emb, out, flagcnt, flaglist);
        hipLaunchKernelGGL(recheck2, dim3(2048), dim3(256), 0, stream,
                           x, emb, flagcnt, flaglist, out);
    } else {
        double* e2 = (double*)d_ws;
        hipLaunchKernelGGL(e2d_kernel, dim3(4096), dim3(256), 0, stream, emb, e2);
        hipMemcpyAsync(out + OFF_CNT, cnt, (size_t)G * M * sizeof(float),
                       hipMemcpyDeviceToDevice, stream);
        hipLaunchKernelGGL(argmin_kernel, dim3((NQ / QT) * G), dim3(256), 0, stream,
                           x, emb, e2, out);
        hipLaunchKernelGGL(gather_kernel, dim3(NROWS / 8), dim3(256), 0, stream,
                           emb, out + OFF_IND, out);
    }
}

// Round 9
// 316.959 us; speedup vs baseline: 1.3707x; 1.3707x over previous
//
#include <hip/hip_runtime.h>

// Problem constants
#define G 4
#define M 4096
#define D 128
#define NQ 16384
#define NROWS 65536                      // total query rows (NQ * G)
#define OFF_IND 8388608                  // NROWS * D
#define OFF_CNT (OFF_IND + NROWS)
#define DELTA 0.08f                      // fp16 single-product margin (~6 sigma)

typedef unsigned int u32;
typedef unsigned short u16;
typedef unsigned long long u64;
typedef __attribute__((ext_vector_type(8))) _Float16 f16x8;
typedef __attribute__((ext_vector_type(4))) float f32x4;
typedef __attribute__((ext_vector_type(16))) float f32x16;

union hpack { f16x8 v; u32 u[4]; _Float16 h[8]; };

// async global->LDS, 16B per lane; lds dst = wave-uniform base (+ lane*16 by HW)
__device__ __forceinline__ void gload16(const void* gsrc, void* ldsdst) {
    __builtin_amdgcn_global_load_lds(
        (const __attribute__((address_space(1))) u32*)gsrc,
        (__attribute__((address_space(3))) u32*)ldsdst,
        16, 0, 0);
}

// order-preserving (score, index) packing: monotone double->u64 map, low 12 bits = m
__device__ __forceinline__ u64 skey(double s, int m) {
    u64 b = (u64)__double_as_longlong(s);
    b = (b & 0x8000000000000000ull) ? ~b : (b | 0x8000000000000000ull);
    return (b & ~0xFFFull) | (u64)(u32)m;
}

// ---------------- fast path ----------------

// prep_all: emb -> efrag (fp16 fragments) + e2f (fp32 row norms) + counts copy
// + flagcnt[4]=0.  efrag chunk (g, mt) of 32 m's at (g*128+mt)*2048 u32 (8 KB).
// Within chunk: [kk*64 + lane] f16x8; lane: m=mt*32+(lane&31), k=kk*16+(lane>>5)*8.
__global__ __launch_bounds__(256) void prep_all(const float* __restrict__ emb,
                                                const float* __restrict__ cnt,
                                                u32* __restrict__ efrag,
                                                float* __restrict__ e2f,
                                                float* __restrict__ outcnt,
                                                int* __restrict__ flagcnt) {
    __shared__ float part[4][32];
    const int tid = threadIdx.x, w = tid >> 6;
    const int g = blockIdx.x >> 7, mt = blockIdx.x & 127;
    u32* chunk = efrag + (size_t)(g * 128 + mt) * 2048;
    float ss = 0.f;
#pragma unroll
    for (int rep = 0; rep < 2; ++rep) {
        const int idx = rep * 256 + tid;           // (kk, lane) slot, 0..511
        const int kk = idx >> 6, lane = idx & 63;
        const int m = mt * 32 + (lane & 31);
        const int k = kk * 16 + (lane >> 5) * 8;
        const float* src = emb + ((size_t)g * M + m) * D + k;
        const float4 a = *(const float4*)src;
        const float4 b = *(const float4*)(src + 4);
        const float v[8] = {a.x, a.y, a.z, a.w, b.x, b.y, b.z, b.w};
        hpack p;
#pragma unroll
        for (int i = 0; i < 8; ++i) {
            ss = fmaf(v[i], v[i], ss);
            p.h[i] = (_Float16)v[i];               // RNE f32->f16
        }
        *(uint4*)(chunk + (size_t)(kk * 64 + lane) * 4) =
            make_uint4(p.u[0], p.u[1], p.u[2], p.u[3]);
    }
    // e2: each (rep,lane) pair covered 16 elems of row m; lanes l and l+32 share m
    ss += __shfl_xor(ss, 32, 64);
    if ((tid & 63) < 32) part[w][tid & 31] = ss;
    __syncthreads();
    if (tid < 32)
        e2f[(size_t)g * M + mt * 32 + tid] =
            part[0][tid] + part[1][tid] + part[2][tid] + part[3][tid];
    else if (tid >= 64 && tid < 96)                // counts copy (32 per block)
        outcnt[(size_t)g * M + mt * 32 + (tid - 64)] = cnt[(size_t)g * M + mt * 32 + (tid - 64)];
    if (blockIdx.x == 0 && tid < 4) flagcnt[tid] = 0;
}

// fp16 32x32x16 MFMA distance+argmin. Block = (g, half, qb): 128 queries x 2048 m.
// Single product fp16(-2x) * fp16(e); margin DELTA guards exactness via recheck.
__global__ __launch_bounds__(256, 4) void vq_mfma5(const float* __restrict__ x,
                                                   const u32* __restrict__ efrag,
                                                   const float* __restrict__ e2f,
                                                   float* __restrict__ out) {
    __shared__ float e2s[2048];       // 8 KB
    __shared__ u32 ebuf[2][2048];     // 2 x 8 KB double buffer

    const int tid = threadIdx.x, w = tid >> 6, lane = tid & 63;
    const int combo = blockIdx.x & 7;              // XCD round-robin friendly
    const int g = combo >> 1, half = combo & 1;
    const int qb = blockIdx.x >> 3;                // 0..127
    const int rot = (qb * 23) & 63;                // chunk-ring stagger

    const float* e2g = e2f + (size_t)g * M + half * 2048;
    for (int i = tid; i < 512; i += 256) ((float4*)e2s)[i] = ((const float4*)e2g)[i];

    // A fragments (this wave's 32 queries): row=lane&31, k=kk*16+(lane>>5)*8
    const int qrow = qb * 128 + w * 32 + (lane & 31);
    f16x8 xh[8];
#pragma unroll
    for (int kk = 0; kk < 8; ++kk) {
        const int k = kk * 16 + (lane >> 5) * 8;
        const float* src = x + ((size_t)qrow * 4 + g) * D + k;
        const float4 a = *(const float4*)src;
        const float4 b = *(const float4*)(src + 4);
        const float v[8] = {a.x, a.y, a.z, a.w, b.x, b.y, b.z, b.w};
        hpack p;
#pragma unroll
        for (int i = 0; i < 8; ++i) p.h[i] = (_Float16)(-2.0f * v[i]);
        xh[kk] = p.v;
    }

    float b1[16], b2[16];
    int i1[16];
#pragma unroll
    for (int r = 0; r < 16; ++r) { b1[r] = 3.4e38f; b2[r] = 3.4e38f; i1[r] = 0; }

    const char* eg = (const char*)(efrag + (size_t)(g * 128 + half * 64) * 2048);
    // prologue: stage chunk rot (8 KB, 2 x 1KB per wave)
#pragma unroll
    for (int j = 0; j < 2; ++j)
        gload16(eg + (size_t)rot * 8192 + w * 2048 + j * 1024 + lane * 16,
                (char*)ebuf[0] + w * 2048 + j * 1024);
    __syncthreads();   // drains vmcnt(0)

    for (int t = 0; t < 64; ++t) {
        const int cur = t & 1;
        const int cidx = (t + rot) & 63;
        if (t < 63) {                 // issue next-chunk async loads early
            const char* src = eg + (size_t)(((t + 1 + rot) & 63)) * 8192;
#pragma unroll
            for (int j = 0; j < 2; ++j)
                gload16(src + w * 2048 + j * 1024 + lane * 16,
                        (char*)ebuf[cur ^ 1] + w * 2048 + j * 1024);
        }
        const f16x8* bp = (const f16x8*)ebuf[cur];
        const float e2c = e2s[cidx * 32 + (lane & 31)];
        f32x16 acc;
#pragma unroll
        for (int r = 0; r < 16; ++r) acc[r] = e2c;   // fold e2[m] into C-init
#pragma unroll
        for (int kk = 0; kk < 8; ++kk)
            acc = __builtin_amdgcn_mfma_f32_32x32x16_f16(xh[kk], bp[kk * 64 + lane],
                                                         acc, 0, 0, 0);
        const int mcol = half * 2048 + cidx * 32 + (lane & 31);
#pragma unroll
        for (int r = 0; r < 16; ++r) {
            const float s = acc[r];
            b2[r] = __builtin_amdgcn_fmed3f(s, b1[r], b2[r]);  // 2nd-best in 1 op
            i1[r] = (s < b1[r]) ? mcol : i1[r];
            b1[r] = fminf(b1[r], s);
        }
        __syncthreads();              // drains vmcnt(0): next chunk staged
    }

    // reduce over the 32 m-lanes within each half-wave; lowest-index tie-break.
    // Write per-query partial {v1, v2, idx} into the query's own x_quant row header.
#pragma unroll
    for (int r = 0; r < 16; ++r) {
        float v1 = b1[r], v2 = b2[r];
        int j1 = i1[r];
#pragma unroll
        for (int off = 1; off < 32; off <<= 1) {
            const float o1 = __shfl_xor(v1, off, 64);
            const int   oj = __shfl_xor(j1, off, 64);
            const float o2 = __shfl_xor(v2, off, 64);
            v2 = fminf(fminf(v2, o2), fmaxf(v1, o1));
            if (o1 < v1 || (o1 == v1 && oj < j1)) { v1 = o1; j1 = oj; }
        }
        if ((lane & 31) == 0) {
            const int q = qb * 128 + w * 32 + (r & 3) + 8 * (r >> 2) + 4 * (lane >> 5);
            float* rowbase = out + (size_t)(q * 4 + g) * D;
            *(float4*)(rowbase + half * 4) =
                make_float4(v1, v2, __int_as_float(j1), 0.f);
        }
    }
}

// gather_merge: per query merge the two half-partials, write ind + count (or flag
// into per-group list + init minkey), then gather the embedding row into x_quant.
__global__ __launch_bounds__(256) void gather_merge(const float* __restrict__ emb,
                                                    float* __restrict__ out,
                                                    int* __restrict__ flagcnt,
                                                    int* __restrict__ flaglist,
                                                    u64* __restrict__ minkey) {
    __shared__ int sm[64];
    const int tid = threadIdx.x;
    const int qid0 = blockIdx.x * 64;               // 64 queries per block, same g
    const int g = qid0 >> 14;
    if (tid < 64) {
        const int qid = qid0 + tid;
        const int n = qid & 16383;
        float* rowbase = out + (size_t)(n * 4 + g) * D;
        const float4 p0 = *(const float4*)(rowbase);
        const float4 p1 = *(const float4*)(rowbase + 4);
        const float v1a = p0.x, v2a = p0.y;
        const float v1b = p1.x, v2b = p1.y;
        const int ia = __float_as_int(p0.z), ib = __float_as_int(p1.z);
        const float v1 = fminf(v1a, v1b);
        const int i = (v1b < v1a) ? ib : ia;        // tie -> half0 (lower index)
        const float v2 = fminf(fminf(v2a, v2b), fmaxf(v1a, v1b));
        out[(size_t)OFF_IND + (size_t)n * 4 + g] = (float)i;   // approx for flagged
        if (v2 - v1 > DELTA) {
            atomicAdd(out + OFF_CNT + (size_t)g * M + i, 1.0f);
        } else {
            const int pos = atomicAdd(&flagcnt[g], 1);
            flaglist[g * NQ + pos] = n;             // recheck fixes ind/count/row
            minkey[(size_t)g * NQ + n] = ~0ull;
        }
        sm[tid] = i;
    }
    __syncthreads();
#pragma unroll
    for (int p = 0; p < 8; ++p) {
        const int t2 = p * 8 + (tid >> 5);
        const int lane = tid & 31;
        const int n = (qid0 + t2) & 16383;
        const int m = sm[t2];
        const float4 v = ((const float4*)(emb + ((size_t)g * M + m) * D))[lane];
        ((float4*)(out + (size_t)(n * 4 + g) * D))[lane] = v;
    }
}

// recheck_chunk: exact fp64 rescan, codebook-chunk-parallel (emb read ONCE).
// Block = (g, 64-m chunk, qsplit). Stages chunk in LDS, streams flagged queries,
// atomicMin of packed (score,idx) key per query.
__global__ __launch_bounds__(256) void recheck_chunk(const float* __restrict__ x,
                                                     const float* __restrict__ emb,
                                                     const int* __restrict__ flagcnt,
                                                     const int* __restrict__ flaglist,
                                                     u64* __restrict__ minkey) {
    __shared__ float es[64][132];     // ~33 KB, padded vs bank conflicts
    __shared__ double ee[64];
    __shared__ float xs[8][128];      // 4 KB: batch of 8 query rows
    __shared__ int qn[8];
    const int tid = threadIdx.x;
    const int g = blockIdx.x >> 7;
    const int mc = (blockIdx.x >> 1) & 63;
    const int qs = blockIdx.x & 1;
    int nf = flagcnt[g];
    if (nf > NQ) nf = NQ;
    if (nf == 0) return;
    // stage emb chunk: rows mc*64 .. +63 (32 KB, read once per block)
    {
        const float* ebase = emb + ((size_t)g * M + mc * 64) * D;
        for (int i = tid; i < 2048; i += 256) {
            const int r = i >> 5, c = i & 31;
            *(float4*)&es[r][c * 4] = ((const float4*)(ebase + (size_t)r * D))[c];
        }
    }
    __syncthreads();
    // exact fp64 row norms for the chunk (once)
    {
        const int tm = tid >> 2, kq = tid & 3;
        double pe = 0.0;
        for (int j = 0; j < 32; ++j) {
            const double v = (double)es[tm][kq * 32 + j];
            pe = fma(v, v, pe);
        }
        pe += __shfl_xor(pe, 1, 64);
        pe += __shfl_xor(pe, 2, 64);
        if (kq == 0) ee[tm] = pe;
    }
    __syncthreads();
    const int tm2 = tid >> 3;         // 0..31 -> m pair (tm2, tm2+32)
    const int ks = tid & 7;           // 0..7, 16 k's each
    const int m0 = mc * 64 + tm2;
    for (int iq0 = qs * 8; iq0 < nf; iq0 += 16) {
        const int nb = min(8, nf - iq0);
        for (int i = tid; i < nb * 32; i += 256) {
            const int b = i >> 5, c = i & 31;
            const int n = flaglist[g * NQ + iq0 + b];
            if (c == 0) qn[b] = n;
            *(float4*)&xs[b][c * 4] = ((const float4*)(x + ((size_t)n * 4 + g) * D))[c];
        }
        __syncthreads();
        for (int b = 0; b < nb; ++b) {
            double d0 = 0.0, d1 = 0.0;
#pragma unroll
            for (int jj = 0; jj < 4; ++jj) {
                const float4 xv = *(const float4*)&xs[b][ks * 16 + jj * 4];
                const float4 e0 = *(const float4*)&es[tm2][ks * 16 + jj * 4];
                const float4 e1 = *(const float4*)&es[tm2 + 32][ks * 16 + jj * 4];
                d0 = fma((double)xv.x, (double)e0.x, d0);
                d0 = fma((double)xv.y, (double)e0.y, d0);
                d0 = fma((double)xv.z, (double)e0.z, d0);
                d0 = fma((double)xv.w, (double)e0.w, d0);
                d1 = fma((double)xv.x, (double)e1.x, d1);
                d1 = fma((double)xv.y, (double)e1.y, d1);
                d1 = fma((double)xv.z, (double)e1.z, d1);
                d1 = fma((double)xv.w, (double)e1.w, d1);
            }
#pragma unroll
            for (int off = 1; off < 8; off <<= 1) {
                d0 += __shfl_xor(d0, off, 64);
                d1 += __shfl_xor(d1, off, 64);
            }
            u64 k = ~0ull;
            if (ks == 0) {
                const u64 k0 = skey(ee[tm2] - 2.0 * d0, m0);
                const u64 k1 = skey(ee[tm2 + 32] - 2.0 * d1, m0 + 32);
                k = (k1 < k0) ? k1 : k0;
            }
#pragma unroll
            for (int off = 8; off < 64; off <<= 1) {
                const u64 ok = __shfl_xor(k, off, 64);
                k = (ok < k) ? ok : k;
            }
            if ((tid & 63) == 0) atomicMin(&minkey[(size_t)g * NQ + qn[b]], k);
        }
        __syncthreads();
    }
}

// recheck_fix: resolve each flagged query from minkey: ind + count + x_quant row.
__global__ __launch_bounds__(256) void recheck_fix(const float* __restrict__ emb,
                                                   const int* __restrict__ flagcnt,
                                                   const int* __restrict__ flaglist,
                                                   const u64* __restrict__ minkey,
                                                   float* __restrict__ out) {
    const int tid = threadIdx.x;
    const int g = blockIdx.x & 3;
    const int slot = tid >> 6, lane = tid & 63;
    int nf = flagcnt[g];
    if (nf > NQ) nf = NQ;
    const int stride = (gridDim.x >> 2) * 4;
    for (int it = (blockIdx.x >> 2) * 4 + slot; it < nf; it += stride) {
        const int n = flaglist[g * NQ + it];
        const int m = (int)(minkey[(size_t)g * NQ + n] & 0xFFFull);
        if (lane == 0) {
            out[(size_t)OFF_IND + (size_t)n * 4 + g] = (float)m;
            atomicAdd(out + OFF_CNT + (size_t)g * M + m, 1.0f);
        }
        if (lane < 32) {
            ((float4*)(out + (size_t)(n * 4 + g) * D))[lane] =
                ((const float4*)(emb + ((size_t)g * M + m) * D))[lane];
        }
    }
}

// ---------------- fallback (exact fp64 path, used only if ws too small) ----------------

#define QT 64
#define MT 128
#define KT 32
#define XPAD 132
#define EPAD 36

__global__ __launch_bounds__(256) void e2d_kernel(const float* __restrict__ emb,
                                                  double* __restrict__ e2) {
    int row = blockIdx.x * 4 + (threadIdx.x >> 6);
    int lane = threadIdx.x & 63;
    const float2 v = ((const float2*)(emb + (size_t)row * D))[lane];
    double s = (double)v.x * (double)v.x + (double)v.y * (double)v.y;
#pragma unroll
    for (int off = 1; off < 64; off <<= 1) s += __shfl_xor(s, off, 64);
    if (lane == 0) e2[row] = s;
}

__global__ __launch_bounds__(256) void argmin_kernel(const float* __restrict__ x,
                                                     const float* __restrict__ emb,
                                                     const double* __restrict__ e2,
                                                     float* __restrict__ out) {
    __shared__ float xs[QT][XPAD];
    __shared__ float es[MT][EPAD];
    const int g = blockIdx.x >> 8;
    const int n0 = (blockIdx.x & 255) * QT;
    const int tid = threadIdx.x;
    const int tm = tid & 15;
    const int tq = tid >> 4;
#pragma unroll
    for (int it = 0; it < 8; ++it) {
        int idx = it * 256 + tid;
        int r = idx >> 5, c2 = idx & 31;
        const float4 v = ((const float4*)(x + ((size_t)((n0 + r) * 4 + g)) * D))[c2];
        *(float4*)&xs[r][c2 * 4] = v;
    }
    double best[4];
    int bm[4];
#pragma unroll
    for (int qi = 0; qi < 4; ++qi) { best[qi] = 1e300; bm[qi] = 0; }
    const double* e2g = e2 + (size_t)g * M;
    const float* eg = emb + (size_t)g * M * D;
    for (int mc = 0; mc < M / MT; ++mc) {
        const int m0 = mc * MT;
        double acc[4][8];
#pragma unroll
        for (int qi = 0; qi < 4; ++qi)
#pragma unroll
            for (int mi = 0; mi < 8; ++mi) acc[qi][mi] = 0.0;
        for (int kc = 0; kc < D / KT; ++kc) {
            __syncthreads();
#pragma unroll
            for (int it = 0; it < 4; ++it) {
                int idx = it * 256 + tid;
                int r = idx >> 3, c2 = idx & 7;
                const float4 v = ((const float4*)(eg + (size_t)(m0 + r) * D + kc * KT))[c2];
                *(float4*)&es[r][c2 * 4] = v;
            }
            __syncthreads();
#pragma unroll
            for (int kk = 0; kk < KT; kk += 4) {
                double xv[4][4];
#pragma unroll
                for (int qi = 0; qi < 4; ++qi) {
                    const float4 v = *(const float4*)&xs[tq + 16 * qi][kc * KT + kk];
                    xv[qi][0] = v.x; xv[qi][1] = v.y; xv[qi][2] = v.z; xv[qi][3] = v.w;
                }
#pragma unroll
                for (int mi = 0; mi < 8; ++mi) {
                    const float4 v = *(const float4*)&es[tm + 16 * mi][kk];
                    const double e0 = v.x, e1 = v.y, e2v = v.z, e3 = v.w;
#pragma unroll
                    for (int qi = 0; qi < 4; ++qi) {
                        acc[qi][mi] = fma(xv[qi][0], e0, acc[qi][mi]);
                        acc[qi][mi] = fma(xv[qi][1], e1, acc[qi][mi]);
                        acc[qi][mi] = fma(xv[qi][2], e2v, acc[qi][mi]);
                        acc[qi][mi] = fma(xv[qi][3], e3, acc[qi][mi]);
                    }
                }
            }
        }
#pragma unroll
        for (int mi = 0; mi < 8; ++mi) {
            const int m = m0 + tm + 16 * mi;
            const double e2m = e2g[m];
#pragma unroll
            for (int qi = 0; qi < 4; ++qi) {
                const double s = e2m - 2.0 * acc[qi][mi];
                if (s < best[qi]) { best[qi] = s; bm[qi] = m; }
            }
        }
    }
#pragma unroll
    for (int qi = 0; qi < 4; ++qi) {
        double v = best[qi];
        int i = bm[qi];
#pragma unroll
        for (int off = 1; off < 16; off <<= 1) {
            const double ov = __shfl_xor(v, off, 64);
            const int oi = __shfl_xor(i, off, 64);
            if (ov < v || (ov == v && oi < i)) { v = ov; i = oi; }
        }
        if (tm == 0) {
            const int n = n0 + tq + 16 * qi;
            out[(size_t)OFF_IND + (size_t)n * 4 + g] = (float)i;
            atomicAdd(out + OFF_CNT + (size_t)g * M + i, 1.0f);
        }
    }
}

__global__ __launch_bounds__(256) void gather_kernel(const float* __restrict__ emb,
                                                     const float* __restrict__ indf,
                                                     float* __restrict__ xq) {
    const int rid = blockIdx.x * 8 + (threadIdx.x >> 5);
    const int lane = threadIdx.x & 31;
    const int g = rid & 3;
    const int m = (int)indf[rid];
    const float4 v = ((const float4*)(emb + ((size_t)g * M + m) * D))[lane];
    ((float4*)(xq + (size_t)rid * D))[lane] = v;
}

// ---------------- launch ----------------

extern "C" void kernel_launch(void* const* d_in, const int* in_sizes, int n_in,
                              void* d_out, int out_size, void* d_ws, size_t ws_size,
                              hipStream_t stream) {
    const float* x   = (const float*)d_in[0];
    const float* emb = (const float*)d_in[1];
    const float* cnt = (const float*)d_in[2];
    float* out = (float*)d_out;

    if (ws_size >= 5046528) {
        u32*   efrag    = (u32*)d_ws;                          // [0, 4194304)  4 MB
        float* e2fp     = (float*)((char*)d_ws + 4194304);     // 64 KB
        int*   flagcnt  = (int*)((char*)d_ws + 4259840);       // 4 ints (pad 256)
        int*   flaglist = (int*)((char*)d_ws + 4260096);       // 4 x NQ ints = 256 KB
        u64*   minkey   = (u64*)((char*)d_ws + 4522240);       // 4 x NQ u64 = 512 KB

        hipLaunchKernelGGL(prep_all, dim3(512), dim3(256), 0, stream,
                           emb, cnt, efrag, e2fp, out + OFF_CNT, flagcnt);
        hipLaunchKernelGGL(vq_mfma5, dim3(1024), dim3(256), 0, stream,
                           x, efrag, e2fp, out);
        hipLaunchKernelGGL(gather_merge, dim3(1024), dim3(256), 0, stream,
                           emb, out, flagcnt, flaglist, minkey);
        hipLaunchKernelGGL(recheck_chunk, dim3(512), dim3(256), 0, stream,
                           x, emb, flagcnt, flaglist, minkey);
        hipLaunchKernelGGL(recheck_fix, dim3(256), dim3(256), 0, stream,
                           emb, flagcnt, flaglist, minkey, out);
    } else {
        double* e2 = (double*)d_ws;
        hipLaunchKernelGGL(e2d_kernel, dim3(4096), dim3(256), 0, stream, emb, e2);
        hipMemcpyAsync(out + OFF_CNT, cnt, (size_t)G * M * sizeof(float),
                       hipMemcpyDeviceToDevice, stream);
        hipLaunchKernelGGL(argmin_kernel, dim3((NQ / QT) * G), dim3(256), 0, stream,
                           x, emb, e2, out);
        hipLaunchKernelGGL(gather_kernel, dim3(NROWS / 8), dim3(256), 0, stream,
                           emb, out + OFF_IND, out);
    }
}